// Round 3
// baseline (1012.803 us; speedup 1.0000x reference)
//
#include <hip/hip_runtime.h>

// B=4, S=2048, E=2048, H=16, D=128, full-head rope. f32 I/O, bf16 MFMA inside.
// Memory plan:
//   d_out: xb [0,32MiB) -> later ctx (same region); Qb [32,64MiB)
//   ws:    Kb [0,32), Vt [32,64), optional Wq_bf [64,88), Wo_bf [88,96)
//   GEMM2 -> f32 ws[0,64MiB), D2D copy to d_out.
// LDS tiles staged by global_load_lds are XOR-swizzled (chunk ^= row&7) to
// break the 16-way bank conflicts of unpadded 128B-stride rows (r6 counters).
// r9: attn paired q-tiles + async V + setprio (798.8 us measured).
// r10: GEMMs rewritten to counted-vmcnt pipeline (T3+T4+T5): tile 256x128,
// BK=64, 512 thr / 8 waves (4Mx2N, 64x64 per wave), ring-3 LDS (144 KiB).
// During tile t, phases stage tile t+2 into ring[(t+2)%3] (last read at t-1,
// provably race-free); boundary = s_waitcnt vmcnt(6) + raw s_barrier (tile
// t+1 arrived; 6 loads of t+2 stay in flight -- never drain to 0, m218).
// 4 phases/tile: {stage || read-once ds_read frags || barrier || setprio(1)
// 8 MFMA setprio(0) || barrier}. Old 128^2 kernels kept for !big fallback.

using frag_ab = __attribute__((ext_vector_type(8))) short;   // 8 bf16 = 4 VGPRs
using frag_cd = __attribute__((ext_vector_type(4))) float;   // 4 f32 acc

__device__ __forceinline__ float b2f(unsigned short u) {
  union { unsigned int i; float f; } v; v.i = ((unsigned int)u) << 16; return v.f;
}
__device__ __forceinline__ unsigned short f2b(float f) {
  union { float f; unsigned int i; } v; v.f = f;
  unsigned int r = v.i + 0x7FFFu + ((v.i >> 16) & 1u);   // RNE
  return (unsigned short)(r >> 16);
}
__device__ __forceinline__ unsigned int pack2(float a, float b) {
  return (unsigned int)f2b(a) | ((unsigned int)f2b(b) << 16);
}
__device__ __forceinline__ void gload16(const unsigned short* g, unsigned short* l) {
  __builtin_amdgcn_global_load_lds(
      (const __attribute__((address_space(1))) unsigned int*)g,
      (__attribute__((address_space(3))) unsigned int*)l, 16, 0, 0);
}

// ---------------------------------------------------------------------------
__global__ __launch_bounds__(256)
void cvt_f32_bf16(const float* __restrict__ in, unsigned short* __restrict__ out) {
  long i = (long)(blockIdx.x * 256 + threadIdx.x) * 8;
  float4 a = *(const float4*)&in[i];
  float4 b = *(const float4*)&in[i + 4];
  uint4 p;
  p.x = pack2(a.x, a.y); p.y = pack2(a.z, a.w);
  p.z = pack2(b.x, b.y); p.w = pack2(b.z, b.w);
  *(uint4*)&out[i] = p;
}

// ---------------------------------------------------------------------------
// Staging helpers. One "round" = 64 rows x 64 cols bf16 (8 KB), 1 gload16 per
// thread at 512 threads (8 waves x 8 rows). XOR chunk swizzle (ch ^= row&7).
// ---------------------------------------------------------------------------
__device__ __forceinline__ void stage_round512(const unsigned short* G, unsigned short* Ls,
                                               int row0, int k0, int rr0,
                                               int wave, int lane) {
  int r = rr0 + wave * 8 + (lane >> 3);
  int srcc = (lane & 7) ^ (r & 7);
  gload16(&G[(long)(row0 + r) * 2048 + k0 + srcc * 8], &Ls[(rr0 + wave * 8) * 64]);
}

// 256-thread variants (old 128^2 fallback kernels)
__device__ __forceinline__ void stage_a_async(const unsigned short* A, unsigned short* As,
                                              int row0, int k0, int wave, int lane, int ldk) {
#pragma unroll
  for (int i = 0; i < 4; i++) {
    int rbase = wave * 32 + i * 8;
    int r = rbase + (lane >> 3);
    int srcc = (lane & 7) ^ (r & 7);
    gload16(&A[(long)(row0 + r) * ldk + k0 + srcc * 8], &As[rbase * 64]);
  }
}
__device__ __forceinline__ void stage_b_cvt(const float* Bw, unsigned short* Bs,
                                            int row0, int k0, int tid) {
#pragma unroll
  for (int i = 0; i < 4; i++) {
    int c = tid + i * 256;                 // chunk id in [0,1024)
    int r = c >> 3, ch = c & 7;
    const float* src = &Bw[(long)(row0 + r) * 2048 + k0 + ch * 8];
    float4 v0 = *(const float4*)src;
    float4 v1 = *(const float4*)(src + 4);
    uint4 p;
    p.x = pack2(v0.x, v0.y); p.y = pack2(v0.z, v0.w);
    p.z = pack2(v1.x, v1.y); p.w = pack2(v1.z, v1.w);
    *(uint4*)&Bs[r * 64 + ((ch ^ (r & 7)) * 8)] = p;
  }
}

// ---------------------------------------------------------------------------
// r10 pipelined GEMM1 (bf16 weights required): qkv = xb @ Wq^T + bias
// Tile 256x128, BK=64, ring-3 LDS, counted vmcnt(6), 4 phases/tile.
// ---------------------------------------------------------------------------
__global__ __launch_bounds__(512, 2)
void gemm_qkv2(const unsigned short* __restrict__ A,    // xb (8192,2048) bf16
               const unsigned short* __restrict__ Bbf,  // wqkv_w bf16 (6144,2048)
               const float* __restrict__ bias,
               unsigned short* __restrict__ Qb,
               unsigned short* __restrict__ Kb,
               unsigned short* __restrict__ Vt) {
  __shared__ __align__(16) unsigned short As[3][256 * 64];
  __shared__ __align__(16) unsigned short Bs[3][128 * 64];
  const int tid  = threadIdx.x;
  const int wave = tid >> 6, lane = tid & 63;
  const int quad = lane >> 4, l16 = lane & 15;
  const int wr = wave >> 1, wc = wave & 1;       // 4M x 2N wave grid
  const int row0A = blockIdx.x * 256;
  const int row0B = blockIdx.y * 128;

  frag_cd acc[4][4];
#pragma unroll
  for (int i = 0; i < 4; i++)
#pragma unroll
    for (int j = 0; j < 4; j++) acc[i][j] = (frag_cd){0.f, 0.f, 0.f, 0.f};

  // prologue: stage tiles 0 and 1 (6 rounds each), keep tile1 partly in flight
#pragma unroll
  for (int tt = 0; tt < 2; ++tt) {
    stage_round512(A,   As[tt], row0A, tt * 64, 0,   wave, lane);
    stage_round512(A,   As[tt], row0A, tt * 64, 64,  wave, lane);
    stage_round512(A,   As[tt], row0A, tt * 64, 128, wave, lane);
    stage_round512(A,   As[tt], row0A, tt * 64, 192, wave, lane);
    stage_round512(Bbf, Bs[tt], row0B, tt * 64, 0,   wave, lane);
    stage_round512(Bbf, Bs[tt], row0B, tt * 64, 64,  wave, lane);
  }
  asm volatile("s_waitcnt vmcnt(6)" ::: "memory");
  __builtin_amdgcn_s_barrier();

  int cur = 0;
  for (int t = 0; t < 32; ++t) {
    const unsigned short* as = As[cur];
    const unsigned short* bs = Bs[cur];
    int nxt2 = cur + 2; if (nxt2 >= 3) nxt2 -= 3;
    const int k2 = (t + 2) * 64;
    const bool pf = (t < 30);

#define LDA_(mi, k2i) (*(const frag_ab*)&as[(wr * 64 + (mi) * 16 + l16) * 64 + ((((k2i) * 4 + quad) ^ (l16 & 7)) * 8)])
#define LDB_(ni, k2i) (*(const frag_ab*)&bs[(wc * 64 + (ni) * 16 + l16) * 64 + ((((k2i) * 4 + quad) ^ (l16 & 7)) * 8)])

    frag_ab a0[2][2], a1[2][2], b0[2][2], b1[2][2];  // [kk2][idx]

    // ---- phase 0: A rounds 0,64 of t+2; read a0,b0; mfma quadrant (0,0)
    if (pf) {
      stage_round512(A, As[nxt2], row0A, k2, 0,  wave, lane);
      stage_round512(A, As[nxt2], row0A, k2, 64, wave, lane);
    }
#pragma unroll
    for (int k2i = 0; k2i < 2; k2i++)
#pragma unroll
      for (int i = 0; i < 2; i++) { a0[k2i][i] = LDA_(i, k2i); b0[k2i][i] = LDB_(i, k2i); }
    __builtin_amdgcn_s_barrier();
    __builtin_amdgcn_s_setprio(1);
#pragma unroll
    for (int k2i = 0; k2i < 2; k2i++)
#pragma unroll
      for (int i = 0; i < 2; i++)
#pragma unroll
        for (int j = 0; j < 2; j++)
          acc[i][j] = __builtin_amdgcn_mfma_f32_16x16x32_bf16(a0[k2i][i], b0[k2i][j], acc[i][j], 0, 0, 0);
    __builtin_amdgcn_s_setprio(0);
    __builtin_amdgcn_s_barrier();

    // ---- phase 1: A rounds 128,192; read b1; quadrant (0,1)
    if (pf) {
      stage_round512(A, As[nxt2], row0A, k2, 128, wave, lane);
      stage_round512(A, As[nxt2], row0A, k2, 192, wave, lane);
    }
#pragma unroll
    for (int k2i = 0; k2i < 2; k2i++)
#pragma unroll
      for (int j = 0; j < 2; j++) b1[k2i][j] = LDB_(2 + j, k2i);
    __builtin_amdgcn_s_barrier();
    __builtin_amdgcn_s_setprio(1);
#pragma unroll
    for (int k2i = 0; k2i < 2; k2i++)
#pragma unroll
      for (int i = 0; i < 2; i++)
#pragma unroll
        for (int j = 0; j < 2; j++)
          acc[i][2 + j] = __builtin_amdgcn_mfma_f32_16x16x32_bf16(a0[k2i][i], b1[k2i][j], acc[i][2 + j], 0, 0, 0);
    __builtin_amdgcn_s_setprio(0);
    __builtin_amdgcn_s_barrier();

    // ---- phase 2: B round 0; read a1; quadrant (1,0)
    if (pf) stage_round512(Bbf, Bs[nxt2], row0B, k2, 0, wave, lane);
#pragma unroll
    for (int k2i = 0; k2i < 2; k2i++)
#pragma unroll
      for (int i = 0; i < 2; i++) a1[k2i][i] = LDA_(2 + i, k2i);
    __builtin_amdgcn_s_barrier();
    __builtin_amdgcn_s_setprio(1);
#pragma unroll
    for (int k2i = 0; k2i < 2; k2i++)
#pragma unroll
      for (int i = 0; i < 2; i++)
#pragma unroll
        for (int j = 0; j < 2; j++)
          acc[2 + i][j] = __builtin_amdgcn_mfma_f32_16x16x32_bf16(a1[k2i][i], b0[k2i][j], acc[2 + i][j], 0, 0, 0);
    __builtin_amdgcn_s_setprio(0);
    __builtin_amdgcn_s_barrier();

    // ---- phase 3: B round 64; quadrant (1,1); boundary counted vmcnt
    if (pf) stage_round512(Bbf, Bs[nxt2], row0B, k2, 64, wave, lane);
    __builtin_amdgcn_s_barrier();
    __builtin_amdgcn_s_setprio(1);
#pragma unroll
    for (int k2i = 0; k2i < 2; k2i++)
#pragma unroll
      for (int i = 0; i < 2; i++)
#pragma unroll
        for (int j = 0; j < 2; j++)
          acc[2 + i][2 + j] = __builtin_amdgcn_mfma_f32_16x16x32_bf16(a1[k2i][i], b1[k2i][j], acc[2 + i][2 + j], 0, 0, 0);
    __builtin_amdgcn_s_setprio(0);
    if (t < 30) asm volatile("s_waitcnt vmcnt(6)" ::: "memory");
    else        asm volatile("s_waitcnt vmcnt(0)" ::: "memory");
    __builtin_amdgcn_s_barrier();
#undef LDA_
#undef LDB_
    cur = cur + 1; if (cur == 3) cur = 0;
  }

  // scatter epilogue (C/D layout: col=l16, row=quad*4+r; m89-verified)
#pragma unroll
  for (int ni = 0; ni < 4; ni++) {
    int col  = row0B + wc * 64 + ni * 16 + l16;
    int h    = col / 384;
    int rem  = col - h * 384;
    int slot = rem >> 7;
    int d    = rem & 127;
    float bv = bias[col];
#pragma unroll
    for (int mi = 0; mi < 4; mi++) {
#pragma unroll
      for (int r = 0; r < 4; r++) {
        int row = row0A + wr * 64 + mi * 16 + quad * 4 + r;
        int b = row >> 11, s = row & 2047;
        unsigned short val = f2b(acc[mi][ni][r] + bv);
        if (slot == 0)      Qb[((long)(b * 16 + h) * 2048 + s) * 128 + d] = val;
        else if (slot == 1) Kb[((long)(b * 16 + h) * 2048 + s) * 128 + d] = val;
        else                Vt[((long)(b * 16 + h) * 128 + d) * 2048 + s] = val;
      }
    }
  }
}

// ---------------------------------------------------------------------------
// r10 pipelined GEMM2 (bf16 weights): out(f32) = ctx @ wo^T + wo_b
// ---------------------------------------------------------------------------
__global__ __launch_bounds__(512, 2)
void gemm_ctx2(const unsigned short* __restrict__ A,    // ctx (8192,2048) bf16
               const unsigned short* __restrict__ Bbf,  // wo_w bf16 (2048,2048)
               const float* __restrict__ bias,
               float* __restrict__ C) {
  __shared__ __align__(16) unsigned short As[3][256 * 64];
  __shared__ __align__(16) unsigned short Bs[3][128 * 64];
  const int tid  = threadIdx.x;
  const int wave = tid >> 6, lane = tid & 63;
  const int quad = lane >> 4, l16 = lane & 15;
  const int wr = wave >> 1, wc = wave & 1;
  const int row0A = blockIdx.x * 256;
  const int row0B = blockIdx.y * 128;

  frag_cd acc[4][4];
#pragma unroll
  for (int i = 0; i < 4; i++)
#pragma unroll
    for (int j = 0; j < 4; j++) acc[i][j] = (frag_cd){0.f, 0.f, 0.f, 0.f};

#pragma unroll
  for (int tt = 0; tt < 2; ++tt) {
    stage_round512(A,   As[tt], row0A, tt * 64, 0,   wave, lane);
    stage_round512(A,   As[tt], row0A, tt * 64, 64,  wave, lane);
    stage_round512(A,   As[tt], row0A, tt * 64, 128, wave, lane);
    stage_round512(A,   As[tt], row0A, tt * 64, 192, wave, lane);
    stage_round512(Bbf, Bs[tt], row0B, tt * 64, 0,   wave, lane);
    stage_round512(Bbf, Bs[tt], row0B, tt * 64, 64,  wave, lane);
  }
  asm volatile("s_waitcnt vmcnt(6)" ::: "memory");
  __builtin_amdgcn_s_barrier();

  int cur = 0;
  for (int t = 0; t < 32; ++t) {
    const unsigned short* as = As[cur];
    const unsigned short* bs = Bs[cur];
    int nxt2 = cur + 2; if (nxt2 >= 3) nxt2 -= 3;
    const int k2 = (t + 2) * 64;
    const bool pf = (t < 30);

#define LDA_(mi, k2i) (*(const frag_ab*)&as[(wr * 64 + (mi) * 16 + l16) * 64 + ((((k2i) * 4 + quad) ^ (l16 & 7)) * 8)])
#define LDB_(ni, k2i) (*(const frag_ab*)&bs[(wc * 64 + (ni) * 16 + l16) * 64 + ((((k2i) * 4 + quad) ^ (l16 & 7)) * 8)])

    frag_ab a0[2][2], a1[2][2], b0[2][2], b1[2][2];

    if (pf) {
      stage_round512(A, As[nxt2], row0A, k2, 0,  wave, lane);
      stage_round512(A, As[nxt2], row0A, k2, 64, wave, lane);
    }
#pragma unroll
    for (int k2i = 0; k2i < 2; k2i++)
#pragma unroll
      for (int i = 0; i < 2; i++) { a0[k2i][i] = LDA_(i, k2i); b0[k2i][i] = LDB_(i, k2i); }
    __builtin_amdgcn_s_barrier();
    __builtin_amdgcn_s_setprio(1);
#pragma unroll
    for (int k2i = 0; k2i < 2; k2i++)
#pragma unroll
      for (int i = 0; i < 2; i++)
#pragma unroll
        for (int j = 0; j < 2; j++)
          acc[i][j] = __builtin_amdgcn_mfma_f32_16x16x32_bf16(a0[k2i][i], b0[k2i][j], acc[i][j], 0, 0, 0);
    __builtin_amdgcn_s_setprio(0);
    __builtin_amdgcn_s_barrier();

    if (pf) {
      stage_round512(A, As[nxt2], row0A, k2, 128, wave, lane);
      stage_round512(A, As[nxt2], row0A, k2, 192, wave, lane);
    }
#pragma unroll
    for (int k2i = 0; k2i < 2; k2i++)
#pragma unroll
      for (int j = 0; j < 2; j++) b1[k2i][j] = LDB_(2 + j, k2i);
    __builtin_amdgcn_s_barrier();
    __builtin_amdgcn_s_setprio(1);
#pragma unroll
    for (int k2i = 0; k2i < 2; k2i++)
#pragma unroll
      for (int i = 0; i < 2; i++)
#pragma unroll
        for (int j = 0; j < 2; j++)
          acc[i][2 + j] = __builtin_amdgcn_mfma_f32_16x16x32_bf16(a0[k2i][i], b1[k2i][j], acc[i][2 + j], 0, 0, 0);
    __builtin_amdgcn_s_setprio(0);
    __builtin_amdgcn_s_barrier();

    if (pf) stage_round512(Bbf, Bs[nxt2], row0B, k2, 0, wave, lane);
#pragma unroll
    for (int k2i = 0; k2i < 2; k2i++)
#pragma unroll
      for (int i = 0; i < 2; i++) a1[k2i][i] = LDA_(2 + i, k2i);
    __builtin_amdgcn_s_barrier();
    __builtin_amdgcn_s_setprio(1);
#pragma unroll
    for (int k2i = 0; k2i < 2; k2i++)
#pragma unroll
      for (int i = 0; i < 2; i++)
#pragma unroll
        for (int j = 0; j < 2; j++)
          acc[2 + i][j] = __builtin_amdgcn_mfma_f32_16x16x32_bf16(a1[k2i][i], b0[k2i][j], acc[2 + i][j], 0, 0, 0);
    __builtin_amdgcn_s_setprio(0);
    __builtin_amdgcn_s_barrier();

    if (pf) stage_round512(Bbf, Bs[nxt2], row0B, k2, 64, wave, lane);
    __builtin_amdgcn_s_barrier();
    __builtin_amdgcn_s_setprio(1);
#pragma unroll
    for (int k2i = 0; k2i < 2; k2i++)
#pragma unroll
      for (int i = 0; i < 2; i++)
#pragma unroll
        for (int j = 0; j < 2; j++)
          acc[2 + i][2 + j] = __builtin_amdgcn_mfma_f32_16x16x32_bf16(a1[k2i][i], b1[k2i][j], acc[2 + i][2 + j], 0, 0, 0);
    __builtin_amdgcn_s_setprio(0);
    if (t < 30) asm volatile("s_waitcnt vmcnt(6)" ::: "memory");
    else        asm volatile("s_waitcnt vmcnt(0)" ::: "memory");
    __builtin_amdgcn_s_barrier();
#undef LDA_
#undef LDB_
    cur = cur + 1; if (cur == 3) cur = 0;
  }

#pragma unroll
  for (int ni = 0; ni < 4; ni++) {
    int col = row0B + wc * 64 + ni * 16 + l16;
    float bv = bias[col];
#pragma unroll
    for (int mi = 0; mi < 4; mi++) {
#pragma unroll
      for (int r = 0; r < 4; r++) {
        int row = row0A + wr * 64 + mi * 16 + quad * 4 + r;
        C[(long)row * 2048 + col] = acc[mi][ni][r] + bv;
      }
    }
  }
}

// ---------------------------------------------------------------------------
// Fallback GEMM1 (f32 weights, 128^2, 2-barrier): qkv = xb @ W^T + bias
// ---------------------------------------------------------------------------
__global__ __launch_bounds__(256)
void gemm_qkv(const unsigned short* __restrict__ A,
              const float* __restrict__ Bw,
              const unsigned short* __restrict__ Bbf,
              const float* __restrict__ bias,
              unsigned short* __restrict__ Qb,
              unsigned short* __restrict__ Kb,
              unsigned short* __restrict__ Vt) {
  __shared__ __align__(16) unsigned short As[128 * 64];
  __shared__ __align__(16) unsigned short Bs[128 * 64];
  const int tid  = threadIdx.x;
  const int wave = tid >> 6, lane = tid & 63;
  const int quad = lane >> 4, l16 = lane & 15;
  const int wm = (wave & 1) * 64, wn = (wave >> 1) * 64;
  const int row0A = blockIdx.x * 128;
  const int row0B = blockIdx.y * 128;

  frag_cd acc[4][4];
#pragma unroll
  for (int i = 0; i < 4; i++)
#pragma unroll
    for (int j = 0; j < 4; j++) acc[i][j] = (frag_cd){0.f, 0.f, 0.f, 0.f};

  for (int k0 = 0; k0 < 2048; k0 += 64) {
    stage_a_async(A, As, row0A, k0, wave, lane, 2048);
    if (Bbf) stage_a_async(Bbf, Bs, row0B, k0, wave, lane, 2048);
    else     stage_b_cvt(Bw, Bs, row0B, k0, tid);
    __syncthreads();
#pragma unroll
    for (int kk = 0; kk < 64; kk += 32) {
      frag_ab af[4], bf[4];
#pragma unroll
      for (int mi = 0; mi < 4; mi++) {
        int row = wm + mi * 16 + l16;
        af[mi] = *(const frag_ab*)&As[row * 64 + (((quad + (kk >> 3)) ^ (l16 & 7)) * 8)];
      }
#pragma unroll
      for (int ni = 0; ni < 4; ni++) {
        int row = wn + ni * 16 + l16;
        bf[ni] = *(const frag_ab*)&Bs[row * 64 + (((quad + (kk >> 3)) ^ (l16 & 7)) * 8)];
      }
#pragma unroll
      for (int mi = 0; mi < 4; mi++)
#pragma unroll
        for (int ni = 0; ni < 4; ni++)
          acc[mi][ni] = __builtin_amdgcn_mfma_f32_16x16x32_bf16(af[mi], bf[ni], acc[mi][ni], 0, 0, 0);
    }
    __syncthreads();
  }
#pragma unroll
  for (int ni = 0; ni < 4; ni++) {
    int col  = row0B + wn + ni * 16 + l16;
    int h    = col / 384;
    int rem  = col - h * 384;
    int slot = rem >> 7;
    int d    = rem & 127;
    float bv = bias[col];
#pragma unroll
    for (int mi = 0; mi < 4; mi++) {
#pragma unroll
      for (int r = 0; r < 4; r++) {
        int row = row0A + wm + mi * 16 + quad * 4 + r;
        int b = row >> 11, s = row & 2047;
        unsigned short val = f2b(acc[mi][ni][r] + bv);
        if (slot == 0)      Qb[((long)(b * 16 + h) * 2048 + s) * 128 + d] = val;
        else if (slot == 1) Kb[((long)(b * 16 + h) * 2048 + s) * 128 + d] = val;
        else                Vt[((long)(b * 16 + h) * 128 + d) * 2048 + s] = val;
      }
    }
  }
}

// ---------------------------------------------------------------------------
// rope in place; attention scale 1/sqrt(128) folded into Q here (free VALU).
// ---------------------------------------------------------------------------
__global__ __launch_bounds__(256)
void rope_inplace(unsigned short* __restrict__ Qb, unsigned short* __restrict__ Kb) {
  int wid  = blockIdx.x * 4 + (threadIdx.x >> 6);
  int j    = threadIdx.x & 63;
  int part = wid & 1;
  int s    = (wid >> 1) & 2047;
  int bh   = wid >> 12;
  unsigned short* buf = part ? Kb : Qb;
  long base = ((long)bh * 2048 + s) * 128;
  unsigned int pr = *(const unsigned int*)&buf[base + 2 * j];
  float x1 = b2f((unsigned short)(pr & 0xFFFFu));
  float x2 = b2f((unsigned short)(pr >> 16));
  float inv = powf(10000.0f, -(float)(2 * j) / 128.0f);
  float ang = (float)s * inv;
  float sn, cs;
  sincosf(ang, &sn, &cs);
  float sc = part ? 1.0f : 0.08838834764831845f;   // Q pre-scaled for attn
  cs *= sc; sn *= sc;
  buf[base + j]      = f2b(x1 * cs - x2 * sn);
  buf[base + 64 + j] = f2b(x1 * sn + x2 * cs);
}

// ---------------------------------------------------------------------------
// Causal flash attention (r9-proven). Q,K (B,H,S,D), Q pre-scaled; V^T.
// Paired q-tiles (qt, 15-qt), async K/V staging, setprio, padded P.
// ---------------------------------------------------------------------------
__global__ __launch_bounds__(256)
void attn_fwd(const unsigned short* __restrict__ Q,
              const unsigned short* __restrict__ K,
              const unsigned short* __restrict__ Vt,
              unsigned short* __restrict__ ctx) {
  __shared__ __align__(16) unsigned short Ks[64 * 128];   // 16-chunk XOR swizzle
  __shared__ __align__(16) unsigned short Vs[128 * 64];   // 8-chunk XOR swizzle
  __shared__ __align__(16) unsigned short Ps[4][32 * 72]; // per-wave P, padded
  const int bh = blockIdx.x;
  const int tid = threadIdx.x;
  const int wave = tid >> 6, lane = tid & 63;
  const int quad = lane >> 4, l16 = lane & 15;
  const long base  = (long)bh * 2048 * 128;
  const long vbase = (long)bh * 262144;
  const int b = bh >> 4, h = bh & 15;
  unsigned short* pw = &Ps[wave][0];

  for (int pass = 0; pass < 2; ++pass) {
    const int qt = pass ? (15 - blockIdx.y) : blockIdx.y;
    const int q0 = qt * 128 + wave * 32;

    frag_ab qf[2][4];
#pragma unroll
    for (int mi = 0; mi < 2; mi++)
#pragma unroll
      for (int ks = 0; ks < 4; ks++)
        qf[mi][ks] = *(const frag_ab*)&Q[base + (long)(q0 + mi * 16 + l16) * 128 + ks * 32 + quad * 8];

    frag_cd o[2][8];
#pragma unroll
    for (int mi = 0; mi < 2; mi++)
#pragma unroll
      for (int ni = 0; ni < 8; ni++) o[mi][ni] = (frag_cd){0.f, 0.f, 0.f, 0.f};
    float m_i[2][4], l_i[2][4];
#pragma unroll
    for (int mi = 0; mi < 2; mi++)
#pragma unroll
      for (int r = 0; r < 4; r++) { m_i[mi][r] = -1.0e30f; l_i[mi][r] = 0.f; }

    const int kv_end = qt * 128 + 128;
    for (int kv0 = 0; kv0 < kv_end; kv0 += 64) {
      __syncthreads();
#pragma unroll
      for (int i = 0; i < 4; i++) {
        int rbase = (wave * 4 + i) * 4;
        int r = rbase + (lane >> 4);
        int srcc = (lane & 15) ^ (r & 15);
        gload16(&K[base + (long)(kv0 + r) * 128 + srcc * 8], &Ks[rbase * 128]);
      }
#pragma unroll
      for (int i = 0; i < 4; i++) {
        int rbase = wave * 32 + i * 8;
        int r = rbase + (lane >> 3);
        int srcc = (lane & 7) ^ (r & 7);
        gload16(&Vt[vbase + (long)r * 2048 + kv0 + srcc * 8], &Vs[rbase * 64]);
      }
      __syncthreads();

      if (kv0 <= q0 + 31) {                 // else: fully masked for this wave
        float p[2][4][4];
        __builtin_amdgcn_s_setprio(1);
#pragma unroll
        for (int nj = 0; nj < 4; nj++) {
          frag_ab kf[4];
          int row = nj * 16 + l16;
#pragma unroll
          for (int ks = 0; ks < 4; ks++)
            kf[ks] = *(const frag_ab*)&Ks[row * 128 + (((ks * 4 + quad) ^ (row & 15)) * 8)];
#pragma unroll
          for (int mi = 0; mi < 2; mi++) {
            frag_cd acc = (frag_cd){0.f, 0.f, 0.f, 0.f};
#pragma unroll
            for (int ks = 0; ks < 4; ks++)
              acc = __builtin_amdgcn_mfma_f32_16x16x32_bf16(qf[mi][ks], kf[ks], acc, 0, 0, 0);
            int colg = kv0 + nj * 16 + l16;
#pragma unroll
            for (int r = 0; r < 4; r++) {
              int rowg = q0 + mi * 16 + quad * 4 + r;
              p[mi][nj][r] = (colg <= rowg) ? acc[r] : -10000.0f;
            }
          }
        }
        __builtin_amdgcn_s_setprio(0);

#pragma unroll
        for (int mi = 0; mi < 2; mi++) {
#pragma unroll
          for (int r = 0; r < 4; r++) {
            float mx = fmaxf(fmaxf(p[mi][0][r], p[mi][1][r]), fmaxf(p[mi][2][r], p[mi][3][r]));
#pragma unroll
            for (int off = 1; off < 16; off <<= 1)
              mx = fmaxf(mx, __shfl_xor(mx, off, 64));
            float mnew  = fmaxf(m_i[mi][r], mx);
            float alpha = __expf(m_i[mi][r] - mnew);
            float rs = 0.f;
#pragma unroll
            for (int nj = 0; nj < 4; nj++) {
              float e = __expf(p[mi][nj][r] - mnew);
              p[mi][nj][r] = e;
              rs += e;
            }
#pragma unroll
            for (int off = 1; off < 16; off <<= 1)
              rs += __shfl_xor(rs, off, 64);
            l_i[mi][r] = l_i[mi][r] * alpha + rs;
            m_i[mi][r] = mnew;
#pragma unroll
            for (int ni = 0; ni < 8; ni++) o[mi][ni][r] *= alpha;
          }
        }

#pragma unroll
        for (int mi = 0; mi < 2; mi++)
#pragma unroll
          for (int nj = 0; nj < 4; nj++)
#pragma unroll
            for (int r = 0; r < 4; r++)
              pw[(mi * 16 + quad * 4 + r) * 72 + nj * 16 + l16] = f2b(p[mi][nj][r]);

        __builtin_amdgcn_s_setprio(1);
#pragma unroll
        for (int ni = 0; ni < 8; ni++) {
          int vrow = ni * 16 + l16;
          frag_ab vf0 = *(const frag_ab*)&Vs[vrow * 64 + ((quad ^ (l16 & 7)) * 8)];
          frag_ab vf1 = *(const frag_ab*)&Vs[vrow * 64 + (((quad + 4) ^ (l16 & 7)) * 8)];
#pragma unroll
          for (int mi = 0; mi < 2; mi++) {
            frag_ab pf0 = *(const frag_ab*)&pw[(mi * 16 + l16) * 72 + quad * 8];
            frag_ab pf1 = *(const frag_ab*)&pw[(mi * 16 + l16) * 72 + 32 + quad * 8];
            o[mi][ni] = __builtin_amdgcn_mfma_f32_16x16x32_bf16(pf0, vf0, o[mi][ni], 0, 0, 0);
            o[mi][ni] = __builtin_amdgcn_mfma_f32_16x16x32_bf16(pf1, vf1, o[mi][ni], 0, 0, 0);
          }
        }
        __builtin_amdgcn_s_setprio(0);
      }
    }

#pragma unroll
    for (int mi = 0; mi < 2; mi++) {
#pragma unroll
      for (int r = 0; r < 4; r++) {
        float inv = 1.0f / fmaxf(l_i[mi][r], 1.0e-20f);
        int s = q0 + mi * 16 + quad * 4 + r;
        long rowb = ((long)b * 2048 + s) * 2048 + h * 128;
#pragma unroll
        for (int ni = 0; ni < 8; ni++)
          ctx[rowb + ni * 16 + l16] = f2b(o[mi][ni][r] * inv);
      }
    }
  }
}

// ---------------------------------------------------------------------------
// Fallback GEMM2 (f32 weights, 128^2): out(f32) = ctx @ wo^T + wo_b
// ---------------------------------------------------------------------------
__global__ __launch_bounds__(256)
void gemm_ctx(const unsigned short* __restrict__ A,
              const float* __restrict__ Bw,
              const unsigned short* __restrict__ Bbf,
              const float* __restrict__ bias,
              float* __restrict__ C) {
  __shared__ __align__(16) unsigned short As[128 * 64];
  __shared__ __align__(16) unsigned short Bs[128 * 64];
  const int tid  = threadIdx.x;
  const int wave = tid >> 6, lane = tid & 63;
  const int quad = lane >> 4, l16 = lane & 15;
  const int wm = (wave & 1) * 64, wn = (wave >> 1) * 64;
  const int row0A = blockIdx.x * 128;
  const int row0B = blockIdx.y * 128;

  frag_cd acc[4][4];
#pragma unroll
  for (int i = 0; i < 4; i++)
#pragma unroll
    for (int j = 0; j < 4; j++) acc[i][j] = (frag_cd){0.f, 0.f, 0.f, 0.f};

  for (int k0 = 0; k0 < 2048; k0 += 64) {
    stage_a_async(A, As, row0A, k0, wave, lane, 2048);
    if (Bbf) stage_a_async(Bbf, Bs, row0B, k0, wave, lane, 2048);
    else     stage_b_cvt(Bw, Bs, row0B, k0, tid);
    __syncthreads();
#pragma unroll
    for (int kk = 0; kk < 64; kk += 32) {
      frag_ab af[4], bf[4];
#pragma unroll
      for (int mi = 0; mi < 4; mi++) {
        int row = wm + mi * 16 + l16;
        af[mi] = *(const frag_ab*)&As[row * 64 + (((quad + (kk >> 3)) ^ (l16 & 7)) * 8)];
      }
#pragma unroll
      for (int ni = 0; ni < 4; ni++) {
        int row = wn + ni * 16 + l16;
        bf[ni] = *(const frag_ab*)&Bs[row * 64 + (((quad + (kk >> 3)) ^ (l16 & 7)) * 8)];
      }
#pragma unroll
      for (int mi = 0; mi < 4; mi++)
#pragma unroll
        for (int ni = 0; ni < 4; ni++)
          acc[mi][ni] = __builtin_amdgcn_mfma_f32_16x16x32_bf16(af[mi], bf[ni], acc[mi][ni], 0, 0, 0);
    }
    __syncthreads();
  }
#pragma unroll
  for (int ni = 0; ni < 4; ni++) {
    int col = row0B + wn + ni * 16 + l16;
    float bv = bias[col];
#pragma unroll
    for (int mi = 0; mi < 4; mi++) {
#pragma unroll
      for (int r = 0; r < 4; r++) {
        int row = row0A + wm + mi * 16 + quad * 4 + r;
        C[(long)row * 2048 + col] = acc[mi][ni][r] + bv;
      }
    }
  }
}

// ---------------------------------------------------------------------------
extern "C" void kernel_launch(void* const* d_in, const int* in_sizes, int n_in,
                              void* d_out, int out_size, void* d_ws, size_t ws_size,
                              hipStream_t stream) {
  const float* x      = (const float*)d_in[0];
  const float* wqkv_w = (const float*)d_in[1];
  const float* wqkv_b = (const float*)d_in[2];
  const float* wo_w   = (const float*)d_in[3];
  const float* wo_b   = (const float*)d_in[4];

  unsigned short* xb  = (unsigned short*)d_out;              // [0,32MiB)
  unsigned short* Qb  = (unsigned short*)d_out + 16777216;   // [32,64MiB)
  unsigned short* Kb  = (unsigned short*)d_ws;               // ws [0,32MiB)
  unsigned short* Vt  = (unsigned short*)d_ws + 16777216;    // ws [32,64MiB)
  unsigned short* ctx = (unsigned short*)d_out;              // over xb (dead)
  float* outf = (float*)d_ws;                                // ws [0,64MiB)

  const bool big = ws_size >= 100663296UL;  // 96 MiB: room for bf16 weights
  unsigned short* Wq = big ? (unsigned short*)d_ws + 33554432 : nullptr; // [64,88MiB)
  unsigned short* Wo = big ? (unsigned short*)d_ws + 46137344 : nullptr; // [88,96MiB)

  // 0) conversions
  cvt_f32_bf16<<<8192, 256, 0, stream>>>(x, xb);
  if (big) {
    cvt_f32_bf16<<<6144, 256, 0, stream>>>(wqkv_w, Wq);
    cvt_f32_bf16<<<2048, 256, 0, stream>>>(wo_w, Wo);
  }
  // 1) QKV projection -> Q,K (bhsd), V^T (bhds)
  if (big) gemm_qkv2<<<dim3(32, 48), 512, 0, stream>>>(xb, Wq, wqkv_b, Qb, Kb, Vt);
  else     gemm_qkv<<<dim3(64, 48), 256, 0, stream>>>(xb, wqkv_w, nullptr, wqkv_b, Qb, Kb, Vt);
  // 2) rope in place (folds attn scale into Q)
  rope_inplace<<<65536, 256, 0, stream>>>(Qb, Kb);
  // 3) flash attention, paired q-tiles -> ctx (B,S,E) bf16
  attn_fwd<<<dim3(64, 8), 256, 0, stream>>>(Qb, Kb, Vt, ctx);
  // 4) output projection -> f32 ws, copy back
  if (big) gemm_ctx2<<<dim3(32, 16), 512, 0, stream>>>(ctx, Wo, wo_b, outf);
  else     gemm_ctx<<<dim3(64, 16), 256, 0, stream>>>(ctx, wo_w, nullptr, wo_b, outf);
  hipMemcpyAsync(d_out, outf, 67108864UL, hipMemcpyDeviceToDevice, stream);
}

// Round 4
// 735.746 us; speedup vs baseline: 1.3766x; 1.3766x over previous
//
#include <hip/hip_runtime.h>

// B=4, S=2048, E=2048, H=16, D=128, full-head rope. f32 I/O, bf16 MFMA inside.
// Memory plan:
//   d_out: xb [0,32MiB) -> later ctx (same region); Qb [32,64MiB)
//   ws:    Kb [0,32), Vt [32,64), optional Wq_bf [64,88), Wo_bf [88,96)
//   GEMM2 -> f32 ws[0,64MiB), D2D copy to d_out.
// LDS tiles staged by global_load_lds are XOR-swizzled (chunk ^= row&7) to
// break the 16-way bank conflicts of unpadded 128B-stride rows (r6 counters).
// r9: attn paired q-tiles + async V + setprio (798.8 us measured).
// r10 FAILED: 256x128/ring-3/4-phase GEMM regressed 273->412 us (1 blk/CU at
// 144KiB LDS, 8 barriers per 32-MFMA K-tile). Lesson: phase-split+counted
// vmcnt only pays in the exact proven 256^2 template; reverted to 128^2.
// r11: swapped QK^T attn: mfma(K,Q) -> S^T in regs; lane (quad,l16) holds
// 16 scores of q-row l16 -> softmax = 16 local ops + 2 shfl_xor (was 64
// shuffles/tile/wave); exp lane-local; P stored as 8x ds_write_b64 (swizzled).

using frag_ab = __attribute__((ext_vector_type(8))) short;   // 8 bf16 = 4 VGPRs
using frag_cd = __attribute__((ext_vector_type(4))) float;   // 4 f32 acc
typedef __attribute__((ext_vector_type(2))) unsigned int uint2v;

__device__ __forceinline__ float b2f(unsigned short u) {
  union { unsigned int i; float f; } v; v.i = ((unsigned int)u) << 16; return v.f;
}
__device__ __forceinline__ unsigned short f2b(float f) {
  union { float f; unsigned int i; } v; v.f = f;
  unsigned int r = v.i + 0x7FFFu + ((v.i >> 16) & 1u);   // RNE
  return (unsigned short)(r >> 16);
}
__device__ __forceinline__ unsigned int pack2(float a, float b) {
  return (unsigned int)f2b(a) | ((unsigned int)f2b(b) << 16);
}
__device__ __forceinline__ void gload16(const unsigned short* g, unsigned short* l) {
  __builtin_amdgcn_global_load_lds(
      (const __attribute__((address_space(1))) unsigned int*)g,
      (__attribute__((address_space(3))) unsigned int*)l, 16, 0, 0);
}

// ---------------------------------------------------------------------------
__global__ __launch_bounds__(256)
void cvt_f32_bf16(const float* __restrict__ in, unsigned short* __restrict__ out) {
  long i = (long)(blockIdx.x * 256 + threadIdx.x) * 8;
  float4 a = *(const float4*)&in[i];
  float4 b = *(const float4*)&in[i + 4];
  uint4 p;
  p.x = pack2(a.x, a.y); p.y = pack2(a.z, a.w);
  p.z = pack2(b.x, b.y); p.w = pack2(b.z, b.w);
  *(uint4*)&out[i] = p;
}

// ---------------------------------------------------------------------------
// Shared GEMM staging (128x64 bf16 tile, XOR-swizzled chunks).
// A always bf16 via global_load_lds. B: bf16 async if Bbf, else f32 inline cvt.
// Fragment read: phys chunk = (quad + kk/8) ^ (l16 & 7).
// ---------------------------------------------------------------------------
__device__ __forceinline__ void stage_a_async(const unsigned short* A, unsigned short* As,
                                              int row0, int k0, int wave, int lane, int ldk) {
#pragma unroll
  for (int i = 0; i < 4; i++) {
    int rbase = wave * 32 + i * 8;
    int r = rbase + (lane >> 3);
    int srcc = (lane & 7) ^ (r & 7);
    gload16(&A[(long)(row0 + r) * ldk + k0 + srcc * 8], &As[rbase * 64]);
  }
}
__device__ __forceinline__ void stage_b_cvt(const float* Bw, unsigned short* Bs,
                                            int row0, int k0, int tid) {
#pragma unroll
  for (int i = 0; i < 4; i++) {
    int c = tid + i * 256;                 // chunk id in [0,1024)
    int r = c >> 3, ch = c & 7;
    const float* src = &Bw[(long)(row0 + r) * 2048 + k0 + ch * 8];
    float4 v0 = *(const float4*)src;
    float4 v1 = *(const float4*)(src + 4);
    uint4 p;
    p.x = pack2(v0.x, v0.y); p.y = pack2(v0.z, v0.w);
    p.z = pack2(v1.x, v1.y); p.w = pack2(v1.z, v1.w);
    *(uint4*)&Bs[r * 64 + ((ch ^ (r & 7)) * 8)] = p;
  }
}

// ---------------------------------------------------------------------------
// GEMM1: qkv = xb @ W^T + bias -> Q (B,H,S,D), K (B,H,S,D), V^T (B,H,D,S)
// ---------------------------------------------------------------------------
__global__ __launch_bounds__(256)
void gemm_qkv(const unsigned short* __restrict__ A,    // xb (8192,2048) bf16
              const float* __restrict__ Bw,            // wqkv_w f32
              const unsigned short* __restrict__ Bbf,  // wqkv_w bf16 or null
              const float* __restrict__ bias,
              unsigned short* __restrict__ Qb,
              unsigned short* __restrict__ Kb,
              unsigned short* __restrict__ Vt) {
  __shared__ __align__(16) unsigned short As[128 * 64];
  __shared__ __align__(16) unsigned short Bs[128 * 64];
  const int tid  = threadIdx.x;
  const int wave = tid >> 6, lane = tid & 63;
  const int quad = lane >> 4, l16 = lane & 15;
  const int wm = (wave & 1) * 64, wn = (wave >> 1) * 64;
  const int row0A = blockIdx.x * 128;
  const int row0B = blockIdx.y * 128;

  frag_cd acc[4][4];
#pragma unroll
  for (int i = 0; i < 4; i++)
#pragma unroll
    for (int j = 0; j < 4; j++) acc[i][j] = (frag_cd){0.f, 0.f, 0.f, 0.f};

  for (int k0 = 0; k0 < 2048; k0 += 64) {
    stage_a_async(A, As, row0A, k0, wave, lane, 2048);
    if (Bbf) stage_a_async(Bbf, Bs, row0B, k0, wave, lane, 2048);
    else     stage_b_cvt(Bw, Bs, row0B, k0, tid);
    __syncthreads();
#pragma unroll
    for (int kk = 0; kk < 64; kk += 32) {
      frag_ab af[4], bf[4];
#pragma unroll
      for (int mi = 0; mi < 4; mi++) {
        int row = wm + mi * 16 + l16;
        af[mi] = *(const frag_ab*)&As[row * 64 + (((quad + (kk >> 3)) ^ (l16 & 7)) * 8)];
      }
#pragma unroll
      for (int ni = 0; ni < 4; ni++) {
        int row = wn + ni * 16 + l16;
        bf[ni] = *(const frag_ab*)&Bs[row * 64 + (((quad + (kk >> 3)) ^ (l16 & 7)) * 8)];
      }
#pragma unroll
      for (int mi = 0; mi < 4; mi++)
#pragma unroll
        for (int ni = 0; ni < 4; ni++)
          acc[mi][ni] = __builtin_amdgcn_mfma_f32_16x16x32_bf16(af[mi], bf[ni], acc[mi][ni], 0, 0, 0);
    }
    __syncthreads();
  }
  // scatter epilogue (C/D layout: col=l16, row=quad*4+r; m89-verified)
#pragma unroll
  for (int ni = 0; ni < 4; ni++) {
    int col  = row0B + wn + ni * 16 + l16;
    int h    = col / 384;
    int rem  = col - h * 384;
    int slot = rem >> 7;
    int d    = rem & 127;
    float bv = bias[col];
#pragma unroll
    for (int mi = 0; mi < 4; mi++) {
#pragma unroll
      for (int r = 0; r < 4; r++) {
        int row = row0A + wm + mi * 16 + quad * 4 + r;
        int b = row >> 11, s = row & 2047;
        unsigned short val = f2b(acc[mi][ni][r] + bv);
        if (slot == 0)      Qb[((long)(b * 16 + h) * 2048 + s) * 128 + d] = val;
        else if (slot == 1) Kb[((long)(b * 16 + h) * 2048 + s) * 128 + d] = val;
        else                Vt[((long)(b * 16 + h) * 128 + d) * 2048 + s] = val;
      }
    }
  }
}

// ---------------------------------------------------------------------------
// rope in place; attention scale 1/sqrt(128) folded into Q here (free VALU).
// ---------------------------------------------------------------------------
__global__ __launch_bounds__(256)
void rope_inplace(unsigned short* __restrict__ Qb, unsigned short* __restrict__ Kb) {
  int wid  = blockIdx.x * 4 + (threadIdx.x >> 6);
  int j    = threadIdx.x & 63;
  int part = wid & 1;
  int s    = (wid >> 1) & 2047;
  int bh   = wid >> 12;
  unsigned short* buf = part ? Kb : Qb;
  long base = ((long)bh * 2048 + s) * 128;
  unsigned int pr = *(const unsigned int*)&buf[base + 2 * j];
  float x1 = b2f((unsigned short)(pr & 0xFFFFu));
  float x2 = b2f((unsigned short)(pr >> 16));
  float inv = powf(10000.0f, -(float)(2 * j) / 128.0f);
  float ang = (float)s * inv;
  float sn, cs;
  sincosf(ang, &sn, &cs);
  float sc = part ? 1.0f : 0.08838834764831845f;   // Q pre-scaled for attn
  cs *= sc; sn *= sc;
  buf[base + j]      = f2b(x1 * cs - x2 * sn);
  buf[base + 64 + j] = f2b(x1 * sn + x2 * cs);
}

// ---------------------------------------------------------------------------
// Causal flash attention. Q,K (B,H,S,D), Q pre-scaled; V^T (B,H,D,S).
// ctx -> (B,S,E) bf16.
// Block = 4 waves, 32 q-rows/wave, kv tile 64; paired q-tiles (qt, 15-qt)
// -> uniform 34 kv-tiles/block, 512 blocks = 2/CU exact (r9-proven).
// r11: QK^T computed SWAPPED: mfma(K,Q) -> S^T; lane (quad,l16) holds
// p[mi][kt][r] = S[q=l16][kv=kt*16+quad*4+r] -> softmax = 16 local ops +
// shfl_xor(16,32); P packed to LDS as b64 (XOR-swizzled [32][64] per wave).
// ---------------------------------------------------------------------------
__global__ __launch_bounds__(256)
void attn_fwd(const unsigned short* __restrict__ Q,
              const unsigned short* __restrict__ K,
              const unsigned short* __restrict__ Vt,
              unsigned short* __restrict__ ctx) {
  __shared__ __align__(16) unsigned short Ks[64 * 128];   // 16-chunk XOR swizzle
  __shared__ __align__(16) unsigned short Vs[128 * 64];   // 8-chunk XOR swizzle
  __shared__ __align__(16) unsigned short Ps[4][32 * 64]; // per-wave P, swizzled
  const int bh = blockIdx.x;
  const int tid = threadIdx.x;
  const int wave = tid >> 6, lane = tid & 63;
  const int quad = lane >> 4, l16 = lane & 15;
  const long base  = (long)bh * 2048 * 128;
  const long vbase = (long)bh * 262144;
  const int b = bh >> 4, h = bh & 15;
  unsigned short* pw = &Ps[wave][0];

  for (int pass = 0; pass < 2; ++pass) {
    const int qt = pass ? (15 - blockIdx.y) : blockIdx.y;
    const int q0 = qt * 128 + wave * 32;

    frag_ab qf[2][4];
#pragma unroll
    for (int mi = 0; mi < 2; mi++)
#pragma unroll
      for (int ks = 0; ks < 4; ks++)
        qf[mi][ks] = *(const frag_ab*)&Q[base + (long)(q0 + mi * 16 + l16) * 128 + ks * 32 + quad * 8];

    frag_cd o[2][8];
#pragma unroll
    for (int mi = 0; mi < 2; mi++)
#pragma unroll
      for (int ni = 0; ni < 8; ni++) o[mi][ni] = (frag_cd){0.f, 0.f, 0.f, 0.f};
    float m_i[2] = {-1.0e30f, -1.0e30f};   // stats for q = l16 (dup across quads)
    float l_i[2] = {0.f, 0.f};

    const int kv_end = qt * 128 + 128;
    for (int kv0 = 0; kv0 < kv_end; kv0 += 64) {
      __syncthreads();
      // K: 64x128, 16-chunk XOR swizzle, async
#pragma unroll
      for (int i = 0; i < 4; i++) {
        int rbase = (wave * 4 + i) * 4;
        int r = rbase + (lane >> 4);
        int srcc = (lane & 15) ^ (r & 15);
        gload16(&K[base + (long)(kv0 + r) * 128 + srcc * 8], &Ks[rbase * 128]);
      }
      // V^T: 128x64, 8-chunk XOR swizzle, async
#pragma unroll
      for (int i = 0; i < 4; i++) {
        int rbase = wave * 32 + i * 8;
        int r = rbase + (lane >> 3);
        int srcc = (lane & 7) ^ (r & 7);
        gload16(&Vt[vbase + (long)r * 2048 + kv0 + srcc * 8], &Vs[rbase * 64]);
      }
      __syncthreads();

      if (kv0 <= q0 + 31) {                 // else: fully masked for this wave
        // S^T = K @ Q^T : p[mi][kt][r] = S[q=l16][kv=kt*16+quad*4+r]
        float p[2][4][4];
        __builtin_amdgcn_s_setprio(1);
#pragma unroll
        for (int kt = 0; kt < 4; kt++) {
          frag_ab kf[4];
          int row = kt * 16 + l16;
#pragma unroll
          for (int ks = 0; ks < 4; ks++)
            kf[ks] = *(const frag_ab*)&Ks[row * 128 + (((ks * 4 + quad) ^ (row & 15)) * 8)];
#pragma unroll
          for (int mi = 0; mi < 2; mi++) {
            frag_cd acc = (frag_cd){0.f, 0.f, 0.f, 0.f};
#pragma unroll
            for (int ks = 0; ks < 4; ks++)
              acc = __builtin_amdgcn_mfma_f32_16x16x32_bf16(kf[ks], qf[mi][ks], acc, 0, 0, 0);
#pragma unroll
            for (int r = 0; r < 4; r++) p[mi][kt][r] = acc[r];
          }
        }
        __builtin_amdgcn_s_setprio(0);

        if (kv0 + 63 > q0) {               // diagonal tiles: apply causal mask
#pragma unroll
          for (int mi = 0; mi < 2; mi++) {
            int qg = q0 + mi * 16 + l16;
#pragma unroll
            for (int kt = 0; kt < 4; kt++)
#pragma unroll
              for (int r = 0; r < 4; r++) {
                int kvg = kv0 + kt * 16 + quad * 4 + r;
                if (kvg > qg) p[mi][kt][r] = -10000.0f;
              }
          }
        }

        // online softmax: stats per q=l16, replicated across quads
        float alpha[2];
#pragma unroll
        for (int mi = 0; mi < 2; mi++) {
          float mx = -1.0e30f;
#pragma unroll
          for (int kt = 0; kt < 4; kt++)
            mx = fmaxf(mx, fmaxf(fmaxf(p[mi][kt][0], p[mi][kt][1]),
                                 fmaxf(p[mi][kt][2], p[mi][kt][3])));
          mx = fmaxf(mx, __shfl_xor(mx, 16, 64));
          mx = fmaxf(mx, __shfl_xor(mx, 32, 64));
          float mnew = fmaxf(m_i[mi], mx);
          alpha[mi] = __expf(m_i[mi] - mnew);
          m_i[mi] = mnew;
          float rs = 0.f;
#pragma unroll
          for (int kt = 0; kt < 4; kt++)
#pragma unroll
            for (int r = 0; r < 4; r++) {
              float e = __expf(p[mi][kt][r] - mnew);
              p[mi][kt][r] = e;
              rs += e;
            }
          rs += __shfl_xor(rs, 16, 64);
          rs += __shfl_xor(rs, 32, 64);
          l_i[mi] = l_i[mi] * alpha[mi] + rs;
        }

        // rescale O (alpha at q=l16 lanes; o rows are q=quad*4+r)
        if (!(__all(alpha[0] == 1.0f) && __all(alpha[1] == 1.0f))) {
#pragma unroll
          for (int mi = 0; mi < 2; mi++) {
            float ar[4];
#pragma unroll
            for (int r = 0; r < 4; r++) ar[r] = __shfl(alpha[mi], quad * 4 + r, 64);
#pragma unroll
            for (int ni = 0; ni < 8; ni++)
#pragma unroll
              for (int r = 0; r < 4; r++) o[mi][ni][r] *= ar[r];
          }
        }

        // P -> LDS: b64 packed, chunk-XOR swizzle (row = mi*16+l16 = q)
#pragma unroll
        for (int mi = 0; mi < 2; mi++) {
          int row = mi * 16 + l16;
#pragma unroll
          for (int kt = 0; kt < 4; kt++) {
            unsigned int u0 = pack2(p[mi][kt][0], p[mi][kt][1]);
            unsigned int u1 = pack2(p[mi][kt][2], p[mi][kt][3]);
            int ch = kt * 2 + (quad >> 1);
            int addr = row * 64 + ((ch ^ (l16 & 7)) * 8) + (quad & 1) * 4;
            *(uint2v*)&pw[addr] = (uint2v){u0, u1};
          }
        }

        // O += P @ V  (pf: A-operand rows q=l16; vf: B-operand rows d=l16)
        frag_ab pf[2][2];
#pragma unroll
        for (int mi = 0; mi < 2; mi++)
#pragma unroll
          for (int ks = 0; ks < 2; ks++)
            pf[mi][ks] = *(const frag_ab*)&pw[(mi * 16 + l16) * 64 +
                                              (((ks * 4 + quad) ^ (l16 & 7)) * 8)];
        __builtin_amdgcn_s_setprio(1);
#pragma unroll
        for (int ni = 0; ni < 8; ni++) {
          int vrow = ni * 16 + l16;
          frag_ab vf0 = *(const frag_ab*)&Vs[vrow * 64 + ((quad ^ (l16 & 7)) * 8)];
          frag_ab vf1 = *(const frag_ab*)&Vs[vrow * 64 + (((quad + 4) ^ (l16 & 7)) * 8)];
#pragma unroll
          for (int mi = 0; mi < 2; mi++) {
            o[mi][ni] = __builtin_amdgcn_mfma_f32_16x16x32_bf16(pf[mi][0], vf0, o[mi][ni], 0, 0, 0);
            o[mi][ni] = __builtin_amdgcn_mfma_f32_16x16x32_bf16(pf[mi][1], vf1, o[mi][ni], 0, 0, 0);
          }
        }
        __builtin_amdgcn_s_setprio(0);
      }
    }

    // ctx row-major (B,S,E); 1/l broadcast from q=l16 lanes to o-rows
#pragma unroll
    for (int mi = 0; mi < 2; mi++) {
      float rl = 1.0f / fmaxf(l_i[mi], 1.0e-20f);
#pragma unroll
      for (int r = 0; r < 4; r++) {
        float inv = __shfl(rl, quad * 4 + r, 64);
        int s = q0 + mi * 16 + quad * 4 + r;
        long rowb = ((long)b * 2048 + s) * 2048 + h * 128;
#pragma unroll
        for (int ni = 0; ni < 8; ni++)
          ctx[rowb + ni * 16 + l16] = f2b(o[mi][ni][r] * inv);
      }
    }
  }
}

// ---------------------------------------------------------------------------
// GEMM2: out(f32) = ctx(bf16 row-major) @ wo^T + wo_b
// ---------------------------------------------------------------------------
__global__ __launch_bounds__(256)
void gemm_ctx(const unsigned short* __restrict__ A,
              const float* __restrict__ Bw,
              const unsigned short* __restrict__ Bbf,
              const float* __restrict__ bias,
              float* __restrict__ C) {
  __shared__ __align__(16) unsigned short As[128 * 64];
  __shared__ __align__(16) unsigned short Bs[128 * 64];
  const int tid  = threadIdx.x;
  const int wave = tid >> 6, lane = tid & 63;
  const int quad = lane >> 4, l16 = lane & 15;
  const int wm = (wave & 1) * 64, wn = (wave >> 1) * 64;
  const int row0A = blockIdx.x * 128;
  const int row0B = blockIdx.y * 128;

  frag_cd acc[4][4];
#pragma unroll
  for (int i = 0; i < 4; i++)
#pragma unroll
    for (int j = 0; j < 4; j++) acc[i][j] = (frag_cd){0.f, 0.f, 0.f, 0.f};

  for (int k0 = 0; k0 < 2048; k0 += 64) {
    stage_a_async(A, As, row0A, k0, wave, lane, 2048);
    if (Bbf) stage_a_async(Bbf, Bs, row0B, k0, wave, lane, 2048);
    else     stage_b_cvt(Bw, Bs, row0B, k0, tid);
    __syncthreads();
#pragma unroll
    for (int kk = 0; kk < 64; kk += 32) {
      frag_ab af[4], bf[4];
#pragma unroll
      for (int mi = 0; mi < 4; mi++) {
        int row = wm + mi * 16 + l16;
        af[mi] = *(const frag_ab*)&As[row * 64 + (((quad + (kk >> 3)) ^ (l16 & 7)) * 8)];
      }
#pragma unroll
      for (int ni = 0; ni < 4; ni++) {
        int row = wn + ni * 16 + l16;
        bf[ni] = *(const frag_ab*)&Bs[row * 64 + (((quad + (kk >> 3)) ^ (l16 & 7)) * 8)];
      }
#pragma unroll
      for (int mi = 0; mi < 4; mi++)
#pragma unroll
        for (int ni = 0; ni < 4; ni++)
          acc[mi][ni] = __builtin_amdgcn_mfma_f32_16x16x32_bf16(af[mi], bf[ni], acc[mi][ni], 0, 0, 0);
    }
    __syncthreads();
  }
#pragma unroll
  for (int ni = 0; ni < 4; ni++) {
    int col = row0B + wn + ni * 16 + l16;
    float bv = bias[col];
#pragma unroll
    for (int mi = 0; mi < 4; mi++) {
#pragma unroll
      for (int r = 0; r < 4; r++) {
        int row = row0A + wm + mi * 16 + quad * 4 + r;
        C[(long)row * 2048 + col] = acc[mi][ni][r] + bv;
      }
    }
  }
}

// ---------------------------------------------------------------------------
extern "C" void kernel_launch(void* const* d_in, const int* in_sizes, int n_in,
                              void* d_out, int out_size, void* d_ws, size_t ws_size,
                              hipStream_t stream) {
  const float* x      = (const float*)d_in[0];
  const float* wqkv_w = (const float*)d_in[1];
  const float* wqkv_b = (const float*)d_in[2];
  const float* wo_w   = (const float*)d_in[3];
  const float* wo_b   = (const float*)d_in[4];

  unsigned short* xb  = (unsigned short*)d_out;              // [0,32MiB)
  unsigned short* Qb  = (unsigned short*)d_out + 16777216;   // [32,64MiB)
  unsigned short* Kb  = (unsigned short*)d_ws;               // ws [0,32MiB)
  unsigned short* Vt  = (unsigned short*)d_ws + 16777216;    // ws [32,64MiB)
  unsigned short* ctx = (unsigned short*)d_out;              // over xb (dead)
  float* outf = (float*)d_ws;                                // ws [0,64MiB)

  const bool big = ws_size >= 100663296UL;  // 96 MiB: room for bf16 weights
  unsigned short* Wq = big ? (unsigned short*)d_ws + 33554432 : nullptr; // [64,88MiB)
  unsigned short* Wo = big ? (unsigned short*)d_ws + 46137344 : nullptr; // [88,96MiB)

  // 0) conversions
  cvt_f32_bf16<<<8192, 256, 0, stream>>>(x, xb);
  if (big) {
    cvt_f32_bf16<<<6144, 256, 0, stream>>>(wqkv_w, Wq);
    cvt_f32_bf16<<<2048, 256, 0, stream>>>(wo_w, Wo);
  }
  // 1) QKV projection -> Q,K (bhsd), V^T (bhds)
  gemm_qkv<<<dim3(64, 48), 256, 0, stream>>>(xb, wqkv_w, Wq, wqkv_b, Qb, Kb, Vt);
  // 2) rope in place (folds attn scale into Q)
  rope_inplace<<<65536, 256, 0, stream>>>(Qb, Kb);
  // 3) flash attention, paired q-tiles, swapped QK^T -> ctx (B,S,E) bf16
  attn_fwd<<<dim3(64, 8), 256, 0, stream>>>(Qb, Kb, Vt, ctx);
  // 4) output projection -> f32 ws, copy back
  gemm_ctx<<<dim3(64, 16), 256, 0, stream>>>(ctx, wo_w, Wo, wo_b, outf);
  hipMemcpyAsync(d_out, outf, 67108864UL, hipMemcpyDeviceToDevice, stream);
}